// Round 5
// baseline (189.612 us; speedup 1.0000x reference)
//
#include <hip/hip_runtime.h>
#include <hip/hip_fp16.h>

#define BATCH 8
#define SEQ   1024
#define DIM   512
#define HEADS 8
#define DHEAD 64
#define MTOT  (BATCH*SEQ)   // 8192

typedef _Float16 f16x8 __attribute__((ext_vector_type(8)));
typedef _Float16 f16x4 __attribute__((ext_vector_type(4)));
typedef float    fx4   __attribute__((ext_vector_type(4)));

#define MFMA16 __builtin_amdgcn_mfma_f32_16x16x32_f16

// async global->LDS, 16B per lane; LDS dest = wave-uniform base + lane*16
__device__ __forceinline__ void gload16(const _Float16* g, _Float16* l) {
    __builtin_amdgcn_global_load_lds(
        (const __attribute__((address_space(1))) unsigned int*)g,
        (__attribute__((address_space(3))) unsigned int*)l, 16, 0, 0);
}

// ---------------------------------------------------------------------------
// Kernel 0: fp32 -> fp16 conversion (x, wq|wk|wv concat, wo)
// ---------------------------------------------------------------------------
__global__ __launch_bounds__(256) void convert_k(
    const float* __restrict__ x,  const float* __restrict__ wq,
    const float* __restrict__ wk, const float* __restrict__ wv,
    const float* __restrict__ wo,
    _Float16* __restrict__ xb, _Float16* __restrict__ wqkvb,
    _Float16* __restrict__ wob)
{
    const int XU = (MTOT*DIM)/4;
    const int WU = (DIM*DIM)/4;
    int idx = blockIdx.x*256 + threadIdx.x;
    if (idx >= XU + 4*WU) return;
    const float* src; _Float16* dst;
    if (idx < XU) { src = x + idx*4; dst = xb + idx*4; }
    else {
        int t = idx - XU; int region = t >> 16; int off = (t & 65535)*4;
        if      (region == 0) { src = wq + off; dst = wqkvb + off; }
        else if (region == 1) { src = wk + off; dst = wqkvb + DIM*DIM + off; }
        else if (region == 2) { src = wv + off; dst = wqkvb + 2*DIM*DIM + off; }
        else                  { src = wo + off; dst = wob + off; }
    }
    float4 v = *(const float4*)src;
    f16x4 o = { (_Float16)v.x, (_Float16)v.y, (_Float16)v.z, (_Float16)v.w };
    *(f16x4*)dst = o;
}

// ---------------------------------------------------------------------------
// Kernel 1: fused QKV projection. Two orientations:
//  blockIdx.x<8 (Q/K): A=W rows (m=out-dim), B=x (n=seq) -> lane's 4 acc = 4
//    consecutive d -> packed f16x4 stores into [b,h,n,d].
//  blockIdx.x>=8 (V): A=x (m=seq), B=W_v -> lane's 4 acc = 4 consecutive n
//    -> packed f16x4 stores into V^T [b,h,d,n].
// glds staging with XOR chunk-swizzle (slot = chunk ^ (row&7)).
// ---------------------------------------------------------------------------
__global__ __launch_bounds__(256,3) void qkv_proj(
    const _Float16* __restrict__ X, const _Float16* __restrict__ W,
    _Float16* __restrict__ Qb, _Float16* __restrict__ Kb,
    _Float16* __restrict__ VTb)
{
    __shared__ _Float16 lA[128*64];
    __shared__ _Float16 lB[128*64];
    const int tid = threadIdx.x;
    const int w = tid>>6, l = tid&63, lr = l&15, lq = l>>4;
    const int wr = w>>1, wc = w&1;
    const int srow = (l>>3);
    const int scol = ((l&7) ^ srow)*8;
    const int sw = lr&7;
    const bool qk = blockIdx.x < 8;
    const _Float16 *pA, *pB;
    int m0, n0;
    if (qk) { m0 = blockIdx.x*128; n0 = blockIdx.y*128;
              pA = W + (size_t)m0*DIM; pB = X + (size_t)n0*DIM; }
    else    { m0 = blockIdx.y*128; n0 = 1024 + (blockIdx.x-8)*128;
              pA = X + (size_t)m0*DIM; pB = W + (size_t)n0*DIM; }
    fx4 acc[4][4] = {};

    for (int k0 = 0; k0 < DIM; k0 += 64) {
        __syncthreads();
#pragma unroll
        for (int t = 0; t < 4; t++) {
            int row = w*32 + t*8;
            gload16(&pA[(size_t)(row+srow)*DIM + k0 + scol], &lA[row*64]);
            gload16(&pB[(size_t)(row+srow)*DIM + k0 + scol], &lB[row*64]);
        }
        __syncthreads();
#pragma unroll
        for (int kb = 0; kb < 2; kb++) {
            f16x8 af[4], bf[4];
#pragma unroll
            for (int cb = 0; cb < 4; cb++)
                bf[cb] = *(const f16x8*)&lB[(wc*64+cb*16+lr)*64 + (((kb*4+lq)^sw))*8];
#pragma unroll
            for (int rb = 0; rb < 4; rb++)
                af[rb] = *(const f16x8*)&lA[(wr*64+rb*16+lr)*64 + (((kb*4+lq)^sw))*8];
#pragma unroll
            for (int rb = 0; rb < 4; rb++)
#pragma unroll
                for (int cb = 0; cb < 4; cb++)
                    acc[rb][cb] = MFMA16(af[rb], bf[cb], acc[rb][cb], 0,0,0);
        }
    }
    if (qk) {
        // m = out-dim, n = seq; 4 acc values = 4 consecutive d
#pragma unroll
        for (int rb = 0; rb < 4; rb++)
#pragma unroll
            for (int cb = 0; cb < 4; cb++) {
                int od = m0 + wr*64 + rb*16 + lq*4;      // out-dim base (x4)
                int sq = n0 + wc*64 + cb*16 + lr;        // seq index
                int b = sq >> 10, n = sq & 1023;
                int which = od >> 9, h = (od >> 6) & 7, d0 = od & 63;
                f16x4 v4;
                if (which == 0) {
#pragma unroll
                    for (int i = 0; i < 4; i++) v4[i] = (_Float16)(acc[rb][cb][i]*0.125f);
                    *(f16x4*)&Qb[((size_t)(b*HEADS+h)*SEQ + n)*DHEAD + d0] = v4;
                } else {
#pragma unroll
                    for (int i = 0; i < 4; i++) v4[i] = (_Float16)acc[rb][cb][i];
                    *(f16x4*)&Kb[((size_t)(b*HEADS+h)*SEQ + n)*DHEAD + d0] = v4;
                }
            }
    } else {
        // m = seq, n = V out-dim; 4 acc values = 4 consecutive n
#pragma unroll
        for (int rb = 0; rb < 4; rb++)
#pragma unroll
            for (int cb = 0; cb < 4; cb++) {
                int inner = (n0 - 1024) + wc*64 + cb*16 + lr;
                int h = inner >> 6, d = inner & 63;
                int m = m0 + wr*64 + rb*16 + lq*4;
                int b = m >> 10, n = m & 1023;
                f16x4 v4;
#pragma unroll
                for (int i = 0; i < 4; i++) v4[i] = (_Float16)acc[rb][cb][i];
                *(f16x4*)&VTb[((size_t)(b*HEADS+h)*DHEAD + d)*SEQ + n] = v4;
            }
    }
}

// ---------------------------------------------------------------------------
// Kernel 2: attention per (b,h). 512 thr = 8 waves = 2 q-halves x 4 j-slices.
// q-tile 128, K/V tiles of 128. Grid 512 blocks @ 2/CU -> one dispatch round.
//   S^T = K_slice.Q^T ; P^T (q-major, stride 48) per-wave LDS ;
//   O^T += VT_slice.P ; cross-wave (4 j-slices) reduction at end.
// ---------------------------------------------------------------------------
__global__ __launch_bounds__(512,4) void attn_k(
    const _Float16* __restrict__ Q, const _Float16* __restrict__ K,
    const _Float16* __restrict__ VT, _Float16* __restrict__ AO)
{
    __shared__ __align__(16) char smem[81920];
    _Float16* lK  = (_Float16*)smem;            // [128][64], chunk-swizzled
    _Float16* lVT = (_Float16*)(smem + 16384);  // [64][128], chunk-swizzled
    _Float16* lPT = (_Float16*)(smem + 32768);  // 8 x [64 q][48]
    const int tid = threadIdx.x;
    const int w = tid>>6, l = tid&63, lr = l&15, lq = l>>4;
    const int qh = w>>2, jw = w&3;
    const int sw = lr&7;
    const int bh = blockIdx.y, q0 = blockIdx.x*128;
    const int b = bh>>3, h = bh&7;
    const _Float16* Qp = Q  + (size_t)bh*SEQ*DHEAD;
    const _Float16* Kp = K  + (size_t)bh*SEQ*DHEAD;
    const _Float16* Vp = VT + (size_t)bh*DHEAD*SEQ;
    _Float16* lPw = lPT + w*3072;

    const int kst_r = (l>>3), kst_c = ((l&7) ^ (l>>3))*8;
    const int vst_r = (l>>4);

    f16x8 qf[4][2];
#pragma unroll
    for (int qg = 0; qg < 4; qg++)
#pragma unroll
        for (int kb = 0; kb < 2; kb++)
            qf[qg][kb] = *(const f16x8*)&Qp[(q0+qh*64+qg*16+lr)*DHEAD + kb*32 + lq*8];

    fx4 O[4][4] = {};          // [db][qg]
    float lsum[4] = {};

    for (int kt = 0; kt < 8; kt++) {
        int k0 = kt*128;
        __syncthreads();
#pragma unroll
        for (int t = 0; t < 2; t++) {          // K tile [128][64]: 2 glds/wave
            int rbase = w*16 + t*8;
            gload16(&Kp[(size_t)(k0+rbase+kst_r)*DHEAD + kst_c], &lK[rbase*64]);
        }
#pragma unroll
        for (int t = 0; t < 2; t++) {          // VT tile [64][128]: 2 glds/wave
            int rbase = w*8 + t*4;
            int r = rbase + vst_r;
            int g = (l&15) ^ (r&7);
            gload16(&Vp[(size_t)r*SEQ + k0 + g*8], &lVT[rbase*128]);
        }
        __syncthreads();

        // ---- S^T for j-slice jw*32..+31; clip+exp; P^T to lPw ----
#pragma unroll
        for (int rb2 = 0; rb2 < 2; rb2++) {
            int jrow = jw*32 + rb2*16 + lr;
            f16x8 kf0 = *(const f16x8*)&lK[jrow*64 + ((lq^sw))*8];
            f16x8 kf1 = *(const f16x8*)&lK[jrow*64 + (((4+lq)^sw))*8];
#pragma unroll
            for (int qg = 0; qg < 4; qg++) {
                fx4 s = {};
                s = MFMA16(kf0, qf[qg][0], s, 0,0,0);
                s = MFMA16(kf1, qf[qg][1], s, 0,0,0);
                f16x4 p4;
#pragma unroll
                for (int i = 0; i < 4; i++) {
                    float p = __expf(__builtin_amdgcn_fmed3f(s[i], 1e-6f, 1.0f));
                    lsum[qg] += p;
                    p4[i] = (_Float16)p;
                }
                *(f16x4*)&lPw[(qg*16+lr)*48 + rb2*16 + lq*4] = p4;
            }
        }
        // ---- O^T += VT_slice . P (same-wave RAW, no barrier) ----
        f16x8 vf[4];
#pragma unroll
        for (int db = 0; db < 4; db++)
            vf[db] = *(const f16x8*)&lVT[(db*16+lr)*128 + (((jw*4+lq)^sw))*8];
#pragma unroll
        for (int qg = 0; qg < 4; qg++) {
            f16x8 pf = *(const f16x8*)&lPw[(qg*16+lr)*48 + lq*8];
#pragma unroll
            for (int db = 0; db < 4; db++)
                O[db][qg] = MFMA16(vf[db], pf, O[db][qg], 0,0,0);
        }
    }

    // ---- reductions ----
#pragma unroll
    for (int qg = 0; qg < 4; qg++) {
        lsum[qg] += __shfl_xor(lsum[qg], 16);
        lsum[qg] += __shfl_xor(lsum[qg], 32);
    }
    __syncthreads();
    float* lsumBuf = (float*)(smem + 53248);        // [8][64] f32
    _Float16* oscr = (_Float16*)smem;               // 6 x [64 q][68] f16
    if (lq == 0) {
#pragma unroll
        for (int qg = 0; qg < 4; qg++)
            lsumBuf[w*64 + qg*16 + lr] = lsum[qg];
    }
    if (jw > 0) {
        _Float16* oo = oscr + (size_t)(qh*3 + (jw-1))*4352;
#pragma unroll
        for (int db = 0; db < 4; db++)
#pragma unroll
            for (int qg = 0; qg < 4; qg++) {
                f16x4 t;
#pragma unroll
                for (int i = 0; i < 4; i++) t[i] = (_Float16)O[db][qg][i];
                *(f16x4*)&oo[(qg*16+lr)*68 + db*16 + lq*4] = t;
            }
    }
    __syncthreads();
    if (jw == 0) {
#pragma unroll
        for (int qg = 0; qg < 4; qg++) {
            float tot = lsum[qg]
                      + lsumBuf[(qh*4+1)*64 + qg*16+lr]
                      + lsumBuf[(qh*4+2)*64 + qg*16+lr]
                      + lsumBuf[(qh*4+3)*64 + qg*16+lr];
            float inv = 1.0f / tot;
            int q = q0 + qh*64 + qg*16 + lr;
            _Float16* aop = AO + ((size_t)(b*SEQ + q)*HEADS + h)*DHEAD;
#pragma unroll
            for (int db = 0; db < 4; db++) {
                fx4 o = O[db][qg];
#pragma unroll
                for (int ww = 1; ww < 4; ww++) {
                    f16x4 t = *(const f16x4*)
                        &oscr[(size_t)(qh*3+ww-1)*4352 + (qg*16+lr)*68 + db*16 + lq*4];
#pragma unroll
                    for (int i = 0; i < 4; i++) o[i] += (float)t[i];
                }
                f16x4 r;
#pragma unroll
                for (int i = 0; i < 4; i++) r[i] = (_Float16)(o[i] * inv);
                *(f16x4*)&aop[db*16 + lq*4] = r;
            }
        }
    }
}

// ---------------------------------------------------------------------------
// Kernel 3: output projection, weight-major: A=wo (m=out-dim 512), B=attn
// (n=seq 8192). Lane's 4 acc = 4 consecutive out-dims -> float4 stores + bias.
// ---------------------------------------------------------------------------
__global__ __launch_bounds__(256,3) void out_proj(
    const _Float16* __restrict__ Wo, const _Float16* __restrict__ Ain,
    const float* __restrict__ bo, float* __restrict__ out)
{
    __shared__ _Float16 lA[128*64];
    __shared__ _Float16 lB[128*64];
    const int tid = threadIdx.x;
    const int m0 = blockIdx.x*128, n0 = blockIdx.y*128;   // m=out-dim, n=seq
    const int w = tid>>6, l = tid&63, lr = l&15, lq = l>>4;
    const int wr = w>>1, wc = w&1;
    const int srow = (l>>3);
    const int scol = ((l&7) ^ srow)*8;
    const int sw = lr&7;
    const _Float16* pA = Wo + (size_t)m0*DIM;
    const _Float16* pB = Ain + (size_t)n0*DIM;
    fx4 acc[4][4] = {};

    for (int k0 = 0; k0 < DIM; k0 += 64) {
        __syncthreads();
#pragma unroll
        for (int t = 0; t < 4; t++) {
            int row = w*32 + t*8;
            gload16(&pA[(size_t)(row+srow)*DIM + k0 + scol], &lA[row*64]);
            gload16(&pB[(size_t)(row+srow)*DIM + k0 + scol], &lB[row*64]);
        }
        __syncthreads();
#pragma unroll
        for (int kb = 0; kb < 2; kb++) {
            f16x8 af[4], bf[4];
#pragma unroll
            for (int cb = 0; cb < 4; cb++)
                bf[cb] = *(const f16x8*)&lB[(wc*64+cb*16+lr)*64 + (((kb*4+lq)^sw))*8];
#pragma unroll
            for (int rb = 0; rb < 4; rb++)
                af[rb] = *(const f16x8*)&lA[(wr*64+rb*16+lr)*64 + (((kb*4+lq)^sw))*8];
#pragma unroll
            for (int rb = 0; rb < 4; rb++)
#pragma unroll
                for (int cb = 0; cb < 4; cb++)
                    acc[rb][cb] = MFMA16(af[rb], bf[cb], acc[rb][cb], 0,0,0);
        }
    }
#pragma unroll
    for (int rb = 0; rb < 4; rb++)
#pragma unroll
        for (int cb = 0; cb < 4; cb++) {
            int od = m0 + wr*64 + rb*16 + lq*4;     // out-dim base (x4)
            int sq = n0 + wc*64 + cb*16 + lr;       // seq index
            float4 bias = *(const float4*)&bo[od];
            float4 r;
            r.x = acc[rb][cb][0] + bias.x;
            r.y = acc[rb][cb][1] + bias.y;
            r.z = acc[rb][cb][2] + bias.z;
            r.w = acc[rb][cb][3] + bias.w;
            *(float4*)&out[(size_t)sq*DIM + od] = r;
        }
}

// ---------------------------------------------------------------------------
extern "C" void kernel_launch(void* const* d_in, const int* in_sizes, int n_in,
                              void* d_out, int out_size, void* d_ws, size_t ws_size,
                              hipStream_t stream)
{
    const float* x  = (const float*)d_in[0];
    const float* wq = (const float*)d_in[1];
    const float* wk = (const float*)d_in[2];
    const float* wv = (const float*)d_in[3];
    const float* wo = (const float*)d_in[4];
    const float* bo = (const float*)d_in[5];
    float* out = (float*)d_out;
    char* ws = (char*)d_ws;

    _Float16* xb    = (_Float16*)(ws);              // 8 MB   [8192][512] f16
    _Float16* wqkvb = (_Float16*)(ws + 8388608);    // 1.5 MB [1536][512]
    _Float16* wob   = (_Float16*)(ws + 9961472);    // 0.5 MB [512][512]
    _Float16* Qb    = (_Float16*)(ws + 10485760);   // 8 MB   [b,h,n,d] (pre-scaled)
    _Float16* Kb    = (_Float16*)(ws + 18874368);   // 8 MB   [b,h,n,d]
    _Float16* VTb   = (_Float16*)(ws + 27262976);   // 8 MB   [b,h,d,n]
    _Float16* attnb = (_Float16*)(ws);              // alias xb (x dead after qkv)

    convert_k<<<5120, 256, 0, stream>>>(x, wq, wk, wv, wo, xb, wqkvb, wob);
    qkv_proj<<<dim3(12, 64), 256, 0, stream>>>(xb, wqkvb, Qb, Kb, VTb);
    attn_k<<<dim3(8, 64), 512, 0, stream>>>(Qb, Kb, VTb, attnb);
    out_proj<<<dim3(4, 64), 256, 0, stream>>>(wob, attnb, bo, out);
}

// Round 6
// 154.652 us; speedup vs baseline: 1.2260x; 1.2260x over previous
//
#include <hip/hip_runtime.h>
#include <hip/hip_fp16.h>

#define BATCH 8
#define SEQ   1024
#define DIM   512
#define HEADS 8
#define DHEAD 64
#define MTOT  (BATCH*SEQ)   // 8192

typedef _Float16 f16x8 __attribute__((ext_vector_type(8)));
typedef _Float16 f16x4 __attribute__((ext_vector_type(4)));
typedef float    fx4   __attribute__((ext_vector_type(4)));

#define MFMA16 __builtin_amdgcn_mfma_f32_16x16x32_f16

// async global->LDS, 16B per lane; LDS dest = wave-uniform base + lane*16
__device__ __forceinline__ void gload16(const _Float16* g, _Float16* l) {
    __builtin_amdgcn_global_load_lds(
        (const __attribute__((address_space(1))) unsigned int*)g,
        (__attribute__((address_space(3))) unsigned int*)l, 16, 0, 0);
}

// ---------------------------------------------------------------------------
// Kernel 0: fp32 -> fp16 conversion (x, wq|wk|wv concat, wo)
// ---------------------------------------------------------------------------
__global__ __launch_bounds__(256) void convert_k(
    const float* __restrict__ x,  const float* __restrict__ wq,
    const float* __restrict__ wk, const float* __restrict__ wv,
    const float* __restrict__ wo,
    _Float16* __restrict__ xb, _Float16* __restrict__ wqkvb,
    _Float16* __restrict__ wob)
{
    const int XU = (MTOT*DIM)/4;
    const int WU = (DIM*DIM)/4;
    int idx = blockIdx.x*256 + threadIdx.x;
    if (idx >= XU + 4*WU) return;
    const float* src; _Float16* dst;
    if (idx < XU) { src = x + idx*4; dst = xb + idx*4; }
    else {
        int t = idx - XU; int region = t >> 16; int off = (t & 65535)*4;
        if      (region == 0) { src = wq + off; dst = wqkvb + off; }
        else if (region == 1) { src = wk + off; dst = wqkvb + DIM*DIM + off; }
        else if (region == 2) { src = wv + off; dst = wqkvb + 2*DIM*DIM + off; }
        else                  { src = wo + off; dst = wob + off; }
    }
    float4 v = *(const float4*)src;
    f16x4 o = { (_Float16)v.x, (_Float16)v.y, (_Float16)v.z, (_Float16)v.w };
    *(f16x4*)dst = o;
}

// ---------------------------------------------------------------------------
// Kernel 1: fused QKV projection. Two orientations:
//  blockIdx.x<8 (Q/K): A=W rows (m=out-dim), B=x (n=seq) -> lane's 4 acc = 4
//    consecutive d -> packed f16x4 stores into [b,h,n,d].
//  blockIdx.x>=8 (V): A=x (m=seq), B=W_v -> lane's 4 acc = 4 consecutive n
//    -> packed f16x4 stores into V^T [b,h,d,n].
// glds staging with XOR chunk-swizzle (slot = chunk ^ (row&7)).
// ---------------------------------------------------------------------------
__global__ __launch_bounds__(256,3) void qkv_proj(
    const _Float16* __restrict__ X, const _Float16* __restrict__ W,
    _Float16* __restrict__ Qb, _Float16* __restrict__ Kb,
    _Float16* __restrict__ VTb)
{
    __shared__ _Float16 lA[128*64];
    __shared__ _Float16 lB[128*64];
    const int tid = threadIdx.x;
    const int w = tid>>6, l = tid&63, lr = l&15, lq = l>>4;
    const int wr = w>>1, wc = w&1;
    const int srow = (l>>3);
    const int scol = ((l&7) ^ srow)*8;
    const int sw = lr&7;
    const bool qk = blockIdx.x < 8;
    const _Float16 *pA, *pB;
    int m0, n0;
    if (qk) { m0 = blockIdx.x*128; n0 = blockIdx.y*128;
              pA = W + (size_t)m0*DIM; pB = X + (size_t)n0*DIM; }
    else    { m0 = blockIdx.y*128; n0 = 1024 + (blockIdx.x-8)*128;
              pA = X + (size_t)m0*DIM; pB = W + (size_t)n0*DIM; }
    fx4 acc[4][4] = {};

    for (int k0 = 0; k0 < DIM; k0 += 64) {
        __syncthreads();
#pragma unroll
        for (int t = 0; t < 4; t++) {
            int row = w*32 + t*8;
            gload16(&pA[(size_t)(row+srow)*DIM + k0 + scol], &lA[row*64]);
            gload16(&pB[(size_t)(row+srow)*DIM + k0 + scol], &lB[row*64]);
        }
        __syncthreads();
#pragma unroll
        for (int kb = 0; kb < 2; kb++) {
            f16x8 af[4], bf[4];
#pragma unroll
            for (int cb = 0; cb < 4; cb++)
                bf[cb] = *(const f16x8*)&lB[(wc*64+cb*16+lr)*64 + (((kb*4+lq)^sw))*8];
#pragma unroll
            for (int rb = 0; rb < 4; rb++)
                af[rb] = *(const f16x8*)&lA[(wr*64+rb*16+lr)*64 + (((kb*4+lq)^sw))*8];
#pragma unroll
            for (int rb = 0; rb < 4; rb++)
#pragma unroll
                for (int cb = 0; cb < 4; cb++)
                    acc[rb][cb] = MFMA16(af[rb], bf[cb], acc[rb][cb], 0,0,0);
        }
    }
    if (qk) {
#pragma unroll
        for (int rb = 0; rb < 4; rb++)
#pragma unroll
            for (int cb = 0; cb < 4; cb++) {
                int od = m0 + wr*64 + rb*16 + lq*4;      // out-dim base (x4)
                int sq = n0 + wc*64 + cb*16 + lr;        // seq index
                int b = sq >> 10, n = sq & 1023;
                int which = od >> 9, h = (od >> 6) & 7, d0 = od & 63;
                f16x4 v4;
                if (which == 0) {
#pragma unroll
                    for (int i = 0; i < 4; i++) v4[i] = (_Float16)(acc[rb][cb][i]*0.125f);
                    *(f16x4*)&Qb[((size_t)(b*HEADS+h)*SEQ + n)*DHEAD + d0] = v4;
                } else {
#pragma unroll
                    for (int i = 0; i < 4; i++) v4[i] = (_Float16)acc[rb][cb][i];
                    *(f16x4*)&Kb[((size_t)(b*HEADS+h)*SEQ + n)*DHEAD + d0] = v4;
                }
            }
    } else {
#pragma unroll
        for (int rb = 0; rb < 4; rb++)
#pragma unroll
            for (int cb = 0; cb < 4; cb++) {
                int inner = (n0 - 1024) + wc*64 + cb*16 + lr;
                int h = inner >> 6, d = inner & 63;
                int m = m0 + wr*64 + rb*16 + lq*4;
                int b = m >> 10, n = m & 1023;
                f16x4 v4;
#pragma unroll
                for (int i = 0; i < 4; i++) v4[i] = (_Float16)acc[rb][cb][i];
                *(f16x4*)&VTb[((size_t)(b*HEADS+h)*DHEAD + d)*SEQ + n] = v4;
            }
    }
}

// ---------------------------------------------------------------------------
// Kernel 2: attention per (b,h), S-transposed + J-SPLIT across waves.
// Block = 256 thr = 4 waves, q-tile 64. Wave w owns j-slice [w*32, w*32+32).
// (R4 version — R5's 512-thr variant spilled VGPRs to scratch: 120MB HBM wr.)
// ---------------------------------------------------------------------------
__global__ __launch_bounds__(256,3) void attn_k(
    const _Float16* __restrict__ Q, const _Float16* __restrict__ K,
    const _Float16* __restrict__ VT, _Float16* __restrict__ AO)
{
    __shared__ __align__(16) char smem[53248];
    _Float16* lK  = (_Float16*)smem;            // [128][64], chunk-swizzled
    _Float16* lVT = (_Float16*)(smem + 16384);  // [64][128], chunk-swizzled
    _Float16* lPT = (_Float16*)(smem + 32768);  // 4 x [64 q][40]
    _Float16* oscr = (_Float16*)smem;           // reuse: 3 x [64 q][68] f16
    float* lsumBuf = (float*)(smem + 32768);    // reuse: [4][64] f32

    const int tid = threadIdx.x;
    const int w = tid>>6, l = tid&63, lr = l&15, lq = l>>4;
    const int sw = lr&7;
    const int bh = blockIdx.y, q0 = blockIdx.x*64;
    const int b = bh>>3, h = bh&7;
    const _Float16* Qp = Q  + (size_t)bh*SEQ*DHEAD;
    const _Float16* Kp = K  + (size_t)bh*SEQ*DHEAD;
    const _Float16* Vp = VT + (size_t)bh*DHEAD*SEQ;
    _Float16* lPw = lPT + w*2560;

    const int kst_r = (l>>3), kst_c = ((l&7) ^ ((l>>3)&7))*8;
    const int vst_r = (l>>4);

    f16x8 qf[4][2];
#pragma unroll
    for (int qg = 0; qg < 4; qg++)
#pragma unroll
        for (int kb = 0; kb < 2; kb++)
            qf[qg][kb] = *(const f16x8*)&Qp[(q0+qg*16+lr)*DHEAD + kb*32 + lq*8];

    fx4 O[4][4] = {};          // [db][qg]; d = db*16+lq*4+i, q = qg*16+lr
    float lsum[4] = {};

    for (int kt = 0; kt < 8; kt++) {
        int k0 = kt*128;
        __syncthreads();
#pragma unroll
        for (int t = 0; t < 4; t++) {          // K tile [128][64]
            int rbase = w*32 + t*8;
            gload16(&Kp[(size_t)(k0+rbase+kst_r)*DHEAD + kst_c], &lK[rbase*64]);
        }
#pragma unroll
        for (int t = 0; t < 4; t++) {          // VT tile [64][128]
            int rbase = w*16 + t*4;
            int r = rbase + vst_r;
            int g = (l&15) ^ (r&7);
            gload16(&Vp[(size_t)r*SEQ + k0 + g*8], &lVT[rbase*128]);
        }
        __syncthreads();

        // ---- S^T for wave's j-slice; clip+exp; P^T (q-major) to lPw ----
#pragma unroll
        for (int rb2 = 0; rb2 < 2; rb2++) {
            int jrow = w*32 + rb2*16 + lr;
            f16x8 kf0 = *(const f16x8*)&lK[jrow*64 + ((lq^sw))*8];
            f16x8 kf1 = *(const f16x8*)&lK[jrow*64 + (((4+lq)^sw))*8];
#pragma unroll
            for (int qg = 0; qg < 4; qg++) {
                fx4 s = {};
                s = MFMA16(kf0, qf[qg][0], s, 0,0,0);
                s = MFMA16(kf1, qf[qg][1], s, 0,0,0);
                f16x4 p4;
#pragma unroll
                for (int i = 0; i < 4; i++) {
                    float p = __expf(__builtin_amdgcn_fmed3f(s[i], 1e-6f, 1.0f));
                    lsum[qg] += p;
                    p4[i] = (_Float16)p;
                }
                *(f16x4*)&lPw[(qg*16+lr)*40 + rb2*16 + lq*4] = p4;
            }
        }
        // ---- O^T += VT_slice . P (same-wave LDS RAW, no barrier needed) ----
        f16x8 vf[4];
#pragma unroll
        for (int db = 0; db < 4; db++)
            vf[db] = *(const f16x8*)&lVT[(db*16+lr)*128 + (((w*4+lq)^sw))*8];
#pragma unroll
        for (int qg = 0; qg < 4; qg++) {
            f16x8 pf = *(const f16x8*)&lPw[(qg*16+lr)*40 + lq*8];
#pragma unroll
            for (int db = 0; db < 4; db++)
                O[db][qg] = MFMA16(vf[db], pf, O[db][qg], 0,0,0);
        }
    }

    // ---- reductions: lsum over lq-quads, then cross-wave via LDS ----
#pragma unroll
    for (int qg = 0; qg < 4; qg++) {
        lsum[qg] += __shfl_xor(lsum[qg], 16);
        lsum[qg] += __shfl_xor(lsum[qg], 32);
    }
    __syncthreads();
    if (lq == 0) {
#pragma unroll
        for (int qg = 0; qg < 4; qg++)
            lsumBuf[w*64 + qg*16 + lr] = lsum[qg];
    }
    if (w > 0) {
        _Float16* oo = oscr + (w-1)*4352;       // [64 q][68]
#pragma unroll
        for (int db = 0; db < 4; db++)
#pragma unroll
            for (int qg = 0; qg < 4; qg++) {
                f16x4 t;
#pragma unroll
                for (int i = 0; i < 4; i++) t[i] = (_Float16)O[db][qg][i];
                *(f16x4*)&oo[(qg*16+lr)*68 + db*16 + lq*4] = t;
            }
    }
    __syncthreads();
    if (w == 0) {
#pragma unroll
        for (int qg = 0; qg < 4; qg++) {
            float tot = lsum[qg] + lsumBuf[64 + qg*16+lr]
                      + lsumBuf[128 + qg*16+lr] + lsumBuf[192 + qg*16+lr];
            float inv = 1.0f / tot;
            int q = q0 + qg*16 + lr;
            _Float16* aop = AO + ((size_t)(b*SEQ + q)*HEADS + h)*DHEAD;
#pragma unroll
            for (int db = 0; db < 4; db++) {
                fx4 o = O[db][qg];
#pragma unroll
                for (int ww = 1; ww < 4; ww++) {
                    f16x4 t = *(const f16x4*)
                        &oscr[(ww-1)*4352 + (qg*16+lr)*68 + db*16 + lq*4];
#pragma unroll
                    for (int i = 0; i < 4; i++) o[i] += (float)t[i];
                }
                f16x4 r;
#pragma unroll
                for (int i = 0; i < 4; i++) r[i] = (_Float16)(o[i] * inv);
                *(f16x4*)&aop[db*16 + lq*4] = r;
            }
        }
    }
}

// ---------------------------------------------------------------------------
// Kernel 3: output projection, weight-major: A=wo (m=out-dim 512), B=attn
// (n=seq 8192). Lane's 4 acc = 4 consecutive out-dims -> float4 stores + bias.
// ---------------------------------------------------------------------------
__global__ __launch_bounds__(256,3) void out_proj(
    const _Float16* __restrict__ Wo, const _Float16* __restrict__ Ain,
    const float* __restrict__ bo, float* __restrict__ out)
{
    __shared__ _Float16 lA[128*64];
    __shared__ _Float16 lB[128*64];
    const int tid = threadIdx.x;
    const int m0 = blockIdx.x*128, n0 = blockIdx.y*128;   // m=out-dim, n=seq
    const int w = tid>>6, l = tid&63, lr = l&15, lq = l>>4;
    const int wr = w>>1, wc = w&1;
    const int srow = (l>>3);
    const int scol = ((l&7) ^ srow)*8;
    const int sw = lr&7;
    const _Float16* pA = Wo + (size_t)m0*DIM;
    const _Float16* pB = Ain + (size_t)n0*DIM;
    fx4 acc[4][4] = {};

    for (int k0 = 0; k0 < DIM; k0 += 64) {
        __syncthreads();
#pragma unroll
        for (int t = 0; t < 4; t++) {
            int row = w*32 + t*8;
            gload16(&pA[(size_t)(row+srow)*DIM + k0 + scol], &lA[row*64]);
            gload16(&pB[(size_t)(row+srow)*DIM + k0 + scol], &lB[row*64]);
        }
        __syncthreads();
#pragma unroll
        for (int kb = 0; kb < 2; kb++) {
            f16x8 af[4], bf[4];
#pragma unroll
            for (int cb = 0; cb < 4; cb++)
                bf[cb] = *(const f16x8*)&lB[(wc*64+cb*16+lr)*64 + (((kb*4+lq)^sw))*8];
#pragma unroll
            for (int rb = 0; rb < 4; rb++)
                af[rb] = *(const f16x8*)&lA[(wr*64+rb*16+lr)*64 + (((kb*4+lq)^sw))*8];
#pragma unroll
            for (int rb = 0; rb < 4; rb++)
#pragma unroll
                for (int cb = 0; cb < 4; cb++)
                    acc[rb][cb] = MFMA16(af[rb], bf[cb], acc[rb][cb], 0,0,0);
        }
    }
#pragma unroll
    for (int rb = 0; rb < 4; rb++)
#pragma unroll
        for (int cb = 0; cb < 4; cb++) {
            int od = m0 + wr*64 + rb*16 + lq*4;
            int sq = n0 + wc*64 + cb*16 + lr;
            float4 bias = *(const float4*)&bo[od];
            float4 r;
            r.x = acc[rb][cb][0] + bias.x;
            r.y = acc[rb][cb][1] + bias.y;
            r.z = acc[rb][cb][2] + bias.z;
            r.w = acc[rb][cb][3] + bias.w;
            *(float4*)&out[(size_t)sq*DIM + od] = r;
        }
}

// ---------------------------------------------------------------------------
extern "C" void kernel_launch(void* const* d_in, const int* in_sizes, int n_in,
                              void* d_out, int out_size, void* d_ws, size_t ws_size,
                              hipStream_t stream)
{
    const float* x  = (const float*)d_in[0];
    const float* wq = (const float*)d_in[1];
    const float* wk = (const float*)d_in[2];
    const float* wv = (const float*)d_in[3];
    const float* wo = (const float*)d_in[4];
    const float* bo = (const float*)d_in[5];
    float* out = (float*)d_out;
    char* ws = (char*)d_ws;

    _Float16* xb    = (_Float16*)(ws);              // 8 MB   [8192][512] f16
    _Float16* wqkvb = (_Float16*)(ws + 8388608);    // 1.5 MB [1536][512]
    _Float16* wob   = (_Float16*)(ws + 9961472);    // 0.5 MB [512][512]
    _Float16* Qb    = (_Float16*)(ws + 10485760);   // 8 MB   [b,h,n,d] (pre-scaled)
    _Float16* Kb    = (_Float16*)(ws + 18874368);   // 8 MB   [b,h,n,d]
    _Float16* VTb   = (_Float16*)(ws + 27262976);   // 8 MB   [b,h,d,n]
    _Float16* attnb = (_Float16*)(ws);              // alias xb (x dead after qkv)

    convert_k<<<5120, 256, 0, stream>>>(x, wq, wk, wv, wo, xb, wqkvb, wob);
    qkv_proj<<<dim3(12, 64), 256, 0, stream>>>(xb, wqkvb, Qb, Kb, VTb);
    attn_k<<<dim3(16, 64), 256, 0, stream>>>(Qb, Kb, VTb, attnb);
    out_proj<<<dim3(4, 64), 256, 0, stream>>>(wob, attnb, bo, out);
}

// Round 7
// 148.280 us; speedup vs baseline: 1.2787x; 1.0430x over previous
//
#include <hip/hip_runtime.h>
#include <hip/hip_fp16.h>

#define BATCH 8
#define SEQ   1024
#define DIM   512
#define HEADS 8
#define DHEAD 64
#define MTOT  (BATCH*SEQ)   // 8192

typedef _Float16 f16x8 __attribute__((ext_vector_type(8)));
typedef _Float16 f16x4 __attribute__((ext_vector_type(4)));
typedef float    fx4   __attribute__((ext_vector_type(4)));

#define MFMA16 __builtin_amdgcn_mfma_f32_16x16x32_f16
#define MFMA16K16 __builtin_amdgcn_mfma_f32_16x16x16f16

// async global->LDS, 16B per lane; LDS dest = wave-uniform base + lane*16
__device__ __forceinline__ void gload16(const _Float16* g, _Float16* l) {
    __builtin_amdgcn_global_load_lds(
        (const __attribute__((address_space(1))) unsigned int*)g,
        (__attribute__((address_space(3))) unsigned int*)l, 16, 0, 0);
}

// ---------------------------------------------------------------------------
// Kernel 0: fp32 -> fp16 conversion (x, wq|wk|wv concat, wo)
// ---------------------------------------------------------------------------
__global__ __launch_bounds__(256) void convert_k(
    const float* __restrict__ x,  const float* __restrict__ wq,
    const float* __restrict__ wk, const float* __restrict__ wv,
    const float* __restrict__ wo,
    _Float16* __restrict__ xb, _Float16* __restrict__ wqkvb,
    _Float16* __restrict__ wob)
{
    const int XU = (MTOT*DIM)/4;
    const int WU = (DIM*DIM)/4;
    int idx = blockIdx.x*256 + threadIdx.x;
    if (idx >= XU + 4*WU) return;
    const float* src; _Float16* dst;
    if (idx < XU) { src = x + idx*4; dst = xb + idx*4; }
    else {
        int t = idx - XU; int region = t >> 16; int off = (t & 65535)*4;
        if      (region == 0) { src = wq + off; dst = wqkvb + off; }
        else if (region == 1) { src = wk + off; dst = wqkvb + DIM*DIM + off; }
        else if (region == 2) { src = wv + off; dst = wqkvb + 2*DIM*DIM + off; }
        else                  { src = wo + off; dst = wob + off; }
    }
    float4 v = *(const float4*)src;
    f16x4 o = { (_Float16)v.x, (_Float16)v.y, (_Float16)v.z, (_Float16)v.w };
    *(f16x4*)dst = o;
}

// ---------------------------------------------------------------------------
// Kernel 1: fused QKV projection (two orientations, packed epilogue stores)
// ---------------------------------------------------------------------------
__global__ __launch_bounds__(256,3) void qkv_proj(
    const _Float16* __restrict__ X, const _Float16* __restrict__ W,
    _Float16* __restrict__ Qb, _Float16* __restrict__ Kb,
    _Float16* __restrict__ VTb)
{
    __shared__ _Float16 lA[128*64];
    __shared__ _Float16 lB[128*64];
    const int tid = threadIdx.x;
    const int w = tid>>6, l = tid&63, lr = l&15, lq = l>>4;
    const int wr = w>>1, wc = w&1;
    const int srow = (l>>3);
    const int scol = ((l&7) ^ srow)*8;
    const int sw = lr&7;
    const bool qk = blockIdx.x < 8;
    const _Float16 *pA, *pB;
    int m0, n0;
    if (qk) { m0 = blockIdx.x*128; n0 = blockIdx.y*128;
              pA = W + (size_t)m0*DIM; pB = X + (size_t)n0*DIM; }
    else    { m0 = blockIdx.y*128; n0 = 1024 + (blockIdx.x-8)*128;
              pA = X + (size_t)m0*DIM; pB = W + (size_t)n0*DIM; }
    fx4 acc[4][4] = {};

    for (int k0 = 0; k0 < DIM; k0 += 64) {
        __syncthreads();
#pragma unroll
        for (int t = 0; t < 4; t++) {
            int row = w*32 + t*8;
            gload16(&pA[(size_t)(row+srow)*DIM + k0 + scol], &lA[row*64]);
            gload16(&pB[(size_t)(row+srow)*DIM + k0 + scol], &lB[row*64]);
        }
        __syncthreads();
#pragma unroll
        for (int kb = 0; kb < 2; kb++) {
            f16x8 af[4], bf[4];
#pragma unroll
            for (int cb = 0; cb < 4; cb++)
                bf[cb] = *(const f16x8*)&lB[(wc*64+cb*16+lr)*64 + (((kb*4+lq)^sw))*8];
#pragma unroll
            for (int rb = 0; rb < 4; rb++)
                af[rb] = *(const f16x8*)&lA[(wr*64+rb*16+lr)*64 + (((kb*4+lq)^sw))*8];
#pragma unroll
            for (int rb = 0; rb < 4; rb++)
#pragma unroll
                for (int cb = 0; cb < 4; cb++)
                    acc[rb][cb] = MFMA16(af[rb], bf[cb], acc[rb][cb], 0,0,0);
        }
    }
    if (qk) {
#pragma unroll
        for (int rb = 0; rb < 4; rb++)
#pragma unroll
            for (int cb = 0; cb < 4; cb++) {
                int od = m0 + wr*64 + rb*16 + lq*4;
                int sq = n0 + wc*64 + cb*16 + lr;
                int b = sq >> 10, n = sq & 1023;
                int which = od >> 9, h = (od >> 6) & 7, d0 = od & 63;
                f16x4 v4;
                if (which == 0) {
#pragma unroll
                    for (int i = 0; i < 4; i++) v4[i] = (_Float16)(acc[rb][cb][i]*0.125f);
                    *(f16x4*)&Qb[((size_t)(b*HEADS+h)*SEQ + n)*DHEAD + d0] = v4;
                } else {
#pragma unroll
                    for (int i = 0; i < 4; i++) v4[i] = (_Float16)acc[rb][cb][i];
                    *(f16x4*)&Kb[((size_t)(b*HEADS+h)*SEQ + n)*DHEAD + d0] = v4;
                }
            }
    } else {
#pragma unroll
        for (int rb = 0; rb < 4; rb++)
#pragma unroll
            for (int cb = 0; cb < 4; cb++) {
                int inner = (n0 - 1024) + wc*64 + cb*16 + lr;
                int h = inner >> 6, d = inner & 63;
                int m = m0 + wr*64 + rb*16 + lq*4;
                int b = m >> 10, n = m & 1023;
                f16x4 v4;
#pragma unroll
                for (int i = 0; i < 4; i++) v4[i] = (_Float16)acc[rb][cb][i];
                *(f16x4*)&VTb[((size_t)(b*HEADS+h)*DHEAD + d)*SEQ + n] = v4;
            }
    }
}

// ---------------------------------------------------------------------------
// Kernel 2: attention per (b,h). 4 waves, q-tile 64, KV-tile 64, j-slice 16.
// KEY: with j-slice=16 + K=16 PV MFMA, the S^T output fragment (m=j=lq*4+i,
// n=q=lr) IS the PV B-operand layout (k=lq*4+i, n=lr) -> P stays in REGISTERS.
// No P LDS round-trip at all. LDS = lK 8K + lVT 8K (both glds, chunk-swizzled).
// ---------------------------------------------------------------------------
__global__ __launch_bounds__(256,3) void attn_k(
    const _Float16* __restrict__ Q, const _Float16* __restrict__ K,
    const _Float16* __restrict__ VT, _Float16* __restrict__ AO)
{
    __shared__ __align__(16) char smem[27648];
    _Float16* lK  = (_Float16*)smem;            // [64][64], chunk-swizzled
    _Float16* lVT = (_Float16*)(smem + 8192);   // [64][64], chunk-swizzled
    _Float16* oscr = (_Float16*)smem;           // reuse: 3 x [64 q][68] f16
    float* lsumBuf = (float*)(smem + 26112);    // reuse: [4][64] f32

    const int tid = threadIdx.x;
    const int w = tid>>6, l = tid&63, lr = l&15, lq = l>>4;
    const int sw = lr&7;
    const int bh = blockIdx.y, q0 = blockIdx.x*64;
    const int b = bh>>3, h = bh&7;
    const _Float16* Qp = Q  + (size_t)bh*SEQ*DHEAD;
    const _Float16* Kp = K  + (size_t)bh*SEQ*DHEAD;
    const _Float16* Vp = VT + (size_t)bh*DHEAD*SEQ;

    const int st_r = (l>>3);                    // staging: 8 lanes/row
    const int st_c = ((l&7) ^ (st_r&7))*8;      // chunk-swizzled column

    f16x8 qf[4][2];
#pragma unroll
    for (int qg = 0; qg < 4; qg++)
#pragma unroll
        for (int kb = 0; kb < 2; kb++)
            qf[qg][kb] = *(const f16x8*)&Qp[(q0+qg*16+lr)*DHEAD + kb*32 + lq*8];

    fx4 O[4][4] = {};          // [db][qg]; d = db*16+lq*4+i, q = qg*16+lr
    float lsum[4] = {};

    for (int kt = 0; kt < 16; kt++) {
        int k0 = kt*64;
        __syncthreads();
#pragma unroll
        for (int t = 0; t < 2; t++) {          // K tile [64][64]: 2 glds/wave
            int rbase = w*16 + t*8;
            int r = rbase + st_r;
            gload16(&Kp[(size_t)(k0+r)*DHEAD + st_c], &lK[rbase*64]);
        }
#pragma unroll
        for (int t = 0; t < 2; t++) {          // VT tile [64][64]: 2 glds/wave
            int rbase = w*16 + t*8;
            int r = rbase + st_r;
            gload16(&Vp[(size_t)r*SEQ + k0 + st_c], &lVT[rbase*64]);
        }
        __syncthreads();

        // ---- S^T for wave's 16-j slice; clip+exp; P stays in registers ----
        f16x8 kf0 = *(const f16x8*)&lK[(w*16+lr)*64 + ((lq^sw))*8];
        f16x8 kf1 = *(const f16x8*)&lK[(w*16+lr)*64 + (((4+lq)^sw))*8];
        f16x4 p4[4];
#pragma unroll
        for (int qg = 0; qg < 4; qg++) {
            fx4 s = {};
            s = MFMA16(kf0, qf[qg][0], s, 0,0,0);
            s = MFMA16(kf1, qf[qg][1], s, 0,0,0);
#pragma unroll
            for (int i = 0; i < 4; i++) {
                float p = __expf(__builtin_amdgcn_fmed3f(s[i], 1e-6f, 1.0f));
                lsum[qg] += p;
                p4[qg][i] = (_Float16)p;
            }
        }
        // ---- O^T += VT_slice . P  (K=16 MFMA, B = p4 directly) ----
#pragma unroll
        for (int db = 0; db < 4; db++) {
            f16x4 vf = *(const f16x4*)
                &lVT[(db*16+lr)*64 + (((w*2+(lq>>1)) ^ sw)<<3) + (lq&1)*4];
#pragma unroll
            for (int qg = 0; qg < 4; qg++)
                O[db][qg] = MFMA16K16(vf, p4[qg], O[db][qg], 0,0,0);
        }
    }

    // ---- reductions: lsum over lq-quads, then cross-wave via LDS ----
#pragma unroll
    for (int qg = 0; qg < 4; qg++) {
        lsum[qg] += __shfl_xor(lsum[qg], 16);
        lsum[qg] += __shfl_xor(lsum[qg], 32);
    }
    __syncthreads();
    if (lq == 0) {
#pragma unroll
        for (int qg = 0; qg < 4; qg++)
            lsumBuf[w*64 + qg*16 + lr] = lsum[qg];
    }
    if (w > 0) {
        _Float16* oo = oscr + (w-1)*4352;       // [64 q][68]
#pragma unroll
        for (int db = 0; db < 4; db++)
#pragma unroll
            for (int qg = 0; qg < 4; qg++) {
                f16x4 t;
#pragma unroll
                for (int i = 0; i < 4; i++) t[i] = (_Float16)O[db][qg][i];
                *(f16x4*)&oo[(qg*16+lr)*68 + db*16 + lq*4] = t;
            }
    }
    __syncthreads();
    if (w == 0) {
#pragma unroll
        for (int qg = 0; qg < 4; qg++) {
            float tot = lsum[qg] + lsumBuf[64 + qg*16+lr]
                      + lsumBuf[128 + qg*16+lr] + lsumBuf[192 + qg*16+lr];
            float inv = 1.0f / tot;
            int q = q0 + qg*16 + lr;
            _Float16* aop = AO + ((size_t)(b*SEQ + q)*HEADS + h)*DHEAD;
#pragma unroll
            for (int db = 0; db < 4; db++) {
                fx4 o = O[db][qg];
#pragma unroll
                for (int ww = 1; ww < 4; ww++) {
                    f16x4 t = *(const f16x4*)
                        &oscr[(ww-1)*4352 + (qg*16+lr)*68 + db*16 + lq*4];
#pragma unroll
                    for (int i = 0; i < 4; i++) o[i] += (float)t[i];
                }
                f16x4 r;
#pragma unroll
                for (int i = 0; i < 4; i++) r[i] = (_Float16)(o[i] * inv);
                *(f16x4*)&aop[db*16 + lq*4] = r;
            }
        }
    }
}

// ---------------------------------------------------------------------------
// Kernel 3: output projection, weight-major (packed float4 epilogue)
// ---------------------------------------------------------------------------
__global__ __launch_bounds__(256,3) void out_proj(
    const _Float16* __restrict__ Wo, const _Float16* __restrict__ Ain,
    const float* __restrict__ bo, float* __restrict__ out)
{
    __shared__ _Float16 lA[128*64];
    __shared__ _Float16 lB[128*64];
    const int tid = threadIdx.x;
    const int m0 = blockIdx.x*128, n0 = blockIdx.y*128;   // m=out-dim, n=seq
    const int w = tid>>6, l = tid&63, lr = l&15, lq = l>>4;
    const int wr = w>>1, wc = w&1;
    const int srow = (l>>3);
    const int scol = ((l&7) ^ srow)*8;
    const int sw = lr&7;
    const _Float16* pA = Wo + (size_t)m0*DIM;
    const _Float16* pB = Ain + (size_t)n0*DIM;
    fx4 acc[4][4] = {};

    for (int k0 = 0; k0 < DIM; k0 += 64) {
        __syncthreads();
#pragma unroll
        for (int t = 0; t < 4; t++) {
            int row = w*32 + t*8;
            gload16(&pA[(size_t)(row+srow)*DIM + k0 + scol], &lA[row*64]);
            gload16(&pB[(size_t)(row+srow)*DIM + k0 + scol], &lB[row*64]);
        }
        __syncthreads();
#pragma unroll
        for (int kb = 0; kb < 2; kb++) {
            f16x8 af[4], bf[4];
#pragma unroll
            for (int cb = 0; cb < 4; cb++)
                bf[cb] = *(const f16x8*)&lB[(wc*64+cb*16+lr)*64 + (((kb*4+lq)^sw))*8];
#pragma unroll
            for (int rb = 0; rb < 4; rb++)
                af[rb] = *(const f16x8*)&lA[(wr*64+rb*16+lr)*64 + (((kb*4+lq)^sw))*8];
#pragma unroll
            for (int rb = 0; rb < 4; rb++)
#pragma unroll
                for (int cb = 0; cb < 4; cb++)
                    acc[rb][cb] = MFMA16(af[rb], bf[cb], acc[rb][cb], 0,0,0);
        }
    }
#pragma unroll
    for (int rb = 0; rb < 4; rb++)
#pragma unroll
        for (int cb = 0; cb < 4; cb++) {
            int od = m0 + wr*64 + rb*16 + lq*4;
            int sq = n0 + wc*64 + cb*16 + lr;
            float4 bias = *(const float4*)&bo[od];
            float4 r;
            r.x = acc[rb][cb][0] + bias.x;
            r.y = acc[rb][cb][1] + bias.y;
            r.z = acc[rb][cb][2] + bias.z;
            r.w = acc[rb][cb][3] + bias.w;
            *(float4*)&out[(size_t)sq*DIM + od] = r;
        }
}

// ---------------------------------------------------------------------------
extern "C" void kernel_launch(void* const* d_in, const int* in_sizes, int n_in,
                              void* d_out, int out_size, void* d_ws, size_t ws_size,
                              hipStream_t stream)
{
    const float* x  = (const float*)d_in[0];
    const float* wq = (const float*)d_in[1];
    const float* wk = (const float*)d_in[2];
    const float* wv = (const float*)d_in[3];
    const float* wo = (const float*)d_in[4];
    const float* bo = (const float*)d_in[5];
    float* out = (float*)d_out;
    char* ws = (char*)d_ws;

    _Float16* xb    = (_Float16*)(ws);              // 8 MB   [8192][512] f16
    _Float16* wqkvb = (_Float16*)(ws + 8388608);    // 1.5 MB [1536][512]
    _Float16* wob   = (_Float16*)(ws + 9961472);    // 0.5 MB [512][512]
    _Float16* Qb    = (_Float16*)(ws + 10485760);   // 8 MB   [b,h,n,d] (pre-scaled)
    _Float16* Kb    = (_Float16*)(ws + 18874368);   // 8 MB   [b,h,n,d]
    _Float16* VTb   = (_Float16*)(ws + 27262976);   // 8 MB   [b,h,d,n]
    _Float16* attnb = (_Float16*)(ws);              // alias xb (x dead after qkv)

    convert_k<<<5120, 256, 0, stream>>>(x, wq, wk, wv, wo, xb, wqkvb, wob);
    qkv_proj<<<dim3(12, 64), 256, 0, stream>>>(xb, wqkvb, Qb, Kb, VTb);
    attn_k<<<dim3(16, 64), 256, 0, stream>>>(Qb, Kb, VTb, attnb);
    out_proj<<<dim3(4, 64), 256, 0, stream>>>(wob, attnb, bo, out);
}